// Round 7
// baseline (183.208 us; speedup 1.0000x reference)
//
#include <hip/hip_runtime.h>

// NormEMAVectorQuantizer on MI355X (gfx950)
// N=8192 tokens, C=32, K=8192 codes, B=32, H*W=256.
// R24 = R17 (proven 120us, the session best) consolidated after the R18-R23
// detours, all of which lost to R17's dense two-sweep:
//  - R18: harvest-in-sweep -> VGPR 164, occupancy cliff, 76us sweep.
//  - R20/R21: sparse per-token rescan = 90/41.5us, latency-bound at 11% VALU;
//    NOT better than the dense second sweep (~28us).
//  - R22/R23: cooperative mega-kernel cannot launch under the harness's graph
//    capture (fallback ran at 143).
// Changes vs R17 (all risk-minimal, numerics bit-identical):
//  (a) ebf stage DELETED: k_max/k_pick stage their emb chunk fp32->bf16
//      in-register during LDS staging (same f2bf rounding -> identical bf16
//      operand bytes -> identical pmax/pick results). Removes prep's 128-block
//      conversion + 512KB ebf round-trip + one pipeline dependency.
//  (b) k_prep = 32 blocks: token norm -> zn/znbf, packed[n]=0 folded in
//      (1 u64 store/thread), loss zero in block 0.
//  (c) __launch_bounds__(256,4) pins k_max/k_pick at the proven 4 blocks/CU
//      (R18's >128-VGPR cliff is the known 2x failure mode).
// Certificate (R17, proven): bf16 dot err <= 2*2^-9 = 0.0078 < eps=0.01 for
// unit rows -> every code that can be the fp32 argmax (incl. all ties) is
// exact-rescored in fp32; key = (fmap(s)<<13)|(8191-code) reproduces numpy
// lowest-index tie-break.
//
// Outputs (float32, concatenated):
//   [0 .. 262144)        z_q_out [B,C,H,W]
//   [262144]             loss (scalar)
//   [262145 .. 270337)   token_ids [B,H,W] as float
//   [270337 .. 532481)   new_embedding [K,C]
//   [532481 .. 540673)   new_cluster_sizes [K]

#define NTOK   8192
#define NCODE  8192
#define CDIM   32
#define HW     256
#define DECAYF 0.99f
#define EPSF   0.01f

#define OUT_ZQ   0
#define OUT_LOSS 262144
#define OUT_IDS  262145
#define OUT_EMB  270337
#define OUT_CS   532481

// workspace byte offsets
#define WS_ZN     0u        // f32 [N,C]        = 1048576
#define WS_ZNBF   1048576u  // bf16 [N,C]       = 524288
#define WS_PMAX   1572864u  // f32 [32][N]      = 1048576
#define WS_PACK   2621440u  // u64 [N]          = 65536   (end 2686976)

#define CHUNK  256
#define NCHUNK (NCODE / CHUNK)  // 32
#define TILES  (CHUNK / 16)     // 16

typedef __attribute__((ext_vector_type(8))) short bf16x8;
typedef __attribute__((ext_vector_type(4))) float f32x4;

__device__ inline unsigned short f2bf(float x) {
    unsigned u = __float_as_uint(x);
    return (unsigned short)((u + 0x7FFFu + ((u >> 16) & 1u)) >> 16);
}
__device__ inline unsigned fmap(float s) {   // monotonic f32 -> u32
    unsigned u = __float_as_uint(s);
    return (u & 0x80000000u) ? ~u : (u | 0x80000000u);
}

// stage one 256x32 chunk of fp32 emb into LDS as bf16, rows padded to 5
// float4 units (80B): banks cycle 20*row%32 -> max 2-way conflict (free).
// Identical LDS image to R17's ebf staging (same f2bf rounding).
__device__ inline void stage_chunk_f32(const float* __restrict__ emb,
                                       int kbase, float4* lbs5, int t) {
    const float* src = emb + (size_t)kbase * CDIM;
#pragma unroll
    for (int j = 0; j < 4; ++j) {
        int u = t + j * 256, row = u >> 2, seg = u & 3;
        const float4* p = (const float4*)(src + row * CDIM + seg * 8);
        float4 x4 = p[0], y4 = p[1];
        union { float4 f4; unsigned short us[8]; } w;
        w.us[0] = f2bf(x4.x); w.us[1] = f2bf(x4.y);
        w.us[2] = f2bf(x4.z); w.us[3] = f2bf(x4.w);
        w.us[4] = f2bf(y4.x); w.us[5] = f2bf(y4.y);
        w.us[6] = f2bf(y4.z); w.us[7] = f2bf(y4.w);
        lbs5[row * 5 + seg] = w.f4;
    }
}

// -------- Kernel A: prep, 32 blocks: norm + zero packed + zero loss -----------
__global__ __launch_bounds__(256) void k_prep(const float* __restrict__ z,
                                              float* __restrict__ zn,
                                              unsigned short* __restrict__ znbf,
                                              unsigned long long* __restrict__ packed,
                                              float* __restrict__ out) {
    int bid = blockIdx.x, t = threadIdx.x;
    int n = bid * 256 + t;
    int b = n >> 8, hw = n & 255;
    const float* zp = z + (size_t)b * (CDIM * HW) + hw;
    float v[CDIM];
    float ss = 0.f;
#pragma unroll
    for (int c = 0; c < CDIM; ++c) {
        float tv = zp[c * HW];                    // coalesced per c
        v[c] = tv;
        ss += tv * tv;
    }
    float d = fmaxf(sqrtf(ss), 1e-12f);
    float* o = zn + (size_t)n * CDIM;
    unsigned short* ob = znbf + (size_t)n * CDIM;
#pragma unroll
    for (int c = 0; c < CDIM; ++c) {
        float tv = v[c] / d;
        o[c] = tv;
        ob[c] = f2bf(tv);
    }
    packed[n] = 0ull;                             // zero for k_pick's atomicMax
    if (bid == 0 && t == 0) out[OUT_LOSS] = 0.f;
}

// -------- Kernel B: MFMA sweep -> pmax[chunk][tok] -----------------------------
__global__ __launch_bounds__(256, 4) void k_max(const unsigned short* __restrict__ znbf,
                                                const float* __restrict__ emb,
                                                float* __restrict__ pmax) {
    __shared__ float4 lbs5[CHUNK * 5];            // 20 KiB, 80B rows
    __shared__ float lmax[256];
    int kbase = blockIdx.y * CHUNK;
    stage_chunk_f32(emb, kbase, lbs5, threadIdx.x);
    __syncthreads();

    int wave = threadIdx.x >> 6, lane = threadIdx.x & 63;
    int col = lane & 15, quad = lane >> 4;
    int wtok = blockIdx.x * 256 + wave * 64;

    bf16x8 a[4];                                  // 4 frags = 64 tokens
#pragma unroll
    for (int f = 0; f < 4; ++f)
        a[f] = *(const bf16x8*)(znbf + (size_t)(wtok + f * 16 + col) * CDIM + quad * 8);

    const bf16x8* bl = (const bf16x8*)lbs5;       // 16B units, row stride 5
    const f32x4 zero4 = {0.f, 0.f, 0.f, 0.f};
    float m[4][4];
#pragma unroll
    for (int f = 0; f < 4; ++f)
#pragma unroll
        for (int r = 0; r < 4; ++r) m[f][r] = -1e30f;

    for (int t = 0; t < TILES; ++t) {
        bf16x8 b = bl[(t * 16 + col) * 5 + quad];
#pragma unroll
        for (int f = 0; f < 4; ++f) {
            f32x4 d = __builtin_amdgcn_mfma_f32_16x16x32_bf16(a[f], b, zero4, 0, 0, 0);
#pragma unroll
            for (int r = 0; r < 4; ++r) m[f][r] = fmaxf(m[f][r], d[r]);
        }
    }
#pragma unroll
    for (int f = 0; f < 4; ++f)
#pragma unroll
        for (int r = 0; r < 4; ++r) {
            float v = m[f][r];
#pragma unroll
            for (int s = 1; s < 16; s <<= 1) v = fmaxf(v, __shfl_xor(v, s));
            if (col == 0) lmax[wave * 64 + f * 16 + quad * 4 + r] = v;
        }
    __syncthreads();
    pmax[(size_t)blockIdx.y * NTOK + blockIdx.x * 256 + threadIdx.x] = lmax[threadIdx.x];
}

// -------- Kernel C: dense rescan vs gmax-eps + inline exact fp32 rescore -------
__global__ __launch_bounds__(256, 4) void k_pick(const unsigned short* __restrict__ znbf,
                                                 const float* __restrict__ zn,
                                                 const float* __restrict__ emb,
                                                 const float* __restrict__ pmax,
                                                 unsigned long long* __restrict__ packed) {
    __shared__ float4 lbs5[CHUNK * 5];            // 20 KiB
    __shared__ float lthr[256];
    int kbase = blockIdx.y * CHUNK;
    stage_chunk_f32(emb, kbase, lbs5, threadIdx.x);
    {   // per-token global threshold: 32 coalesced loads
        int tok = blockIdx.x * 256 + threadIdx.x;
        float mx = -1e30f;
#pragma unroll
        for (int ch = 0; ch < NCHUNK; ++ch)
            mx = fmaxf(mx, pmax[(size_t)ch * NTOK + tok]);
        lthr[threadIdx.x] = mx - EPSF;
    }
    __syncthreads();

    int wave = threadIdx.x >> 6, lane = threadIdx.x & 63;
    int col = lane & 15, quad = lane >> 4;
    int wtok = blockIdx.x * 256 + wave * 64;

    bf16x8 a[4];
#pragma unroll
    for (int f = 0; f < 4; ++f)
        a[f] = *(const bf16x8*)(znbf + (size_t)(wtok + f * 16 + col) * CDIM + quad * 8);

    float thr[4][4];
#pragma unroll
    for (int f = 0; f < 4; ++f)
#pragma unroll
        for (int r = 0; r < 4; ++r)
            thr[f][r] = lthr[wave * 64 + f * 16 + quad * 4 + r];

    const bf16x8* bl = (const bf16x8*)lbs5;
    const f32x4 zero4 = {0.f, 0.f, 0.f, 0.f};

    for (int t = 0; t < TILES; ++t) {
        bf16x8 b = bl[(t * 16 + col) * 5 + quad];
#pragma unroll
        for (int f = 0; f < 4; ++f) {
            f32x4 d = __builtin_amdgcn_mfma_f32_16x16x32_bf16(a[f], b, zero4, 0, 0, 0);
#pragma unroll
            for (int r = 0; r < 4; ++r) {
                if (d[r] >= thr[f][r]) {          // rare: ~1.05/token total
                    int tok = wtok + f * 16 + quad * 4 + r;
                    int code = kbase + t * 16 + col;
                    const float* zp = zn + (size_t)tok * CDIM;
                    const float* ep = emb + (size_t)code * CDIM;
                    float a0 = 0.f, a1 = 0.f, a2 = 0.f, a3 = 0.f;
#pragma unroll
                    for (int j = 0; j < 8; ++j) {
                        a0 = __builtin_fmaf(zp[4 * j + 0], ep[4 * j + 0], a0);
                        a1 = __builtin_fmaf(zp[4 * j + 1], ep[4 * j + 1], a1);
                        a2 = __builtin_fmaf(zp[4 * j + 2], ep[4 * j + 2], a2);
                        a3 = __builtin_fmaf(zp[4 * j + 3], ep[4 * j + 3], a3);
                    }
                    float s = (a0 + a1) + (a2 + a3);
                    atomicMax(packed + tok, ((unsigned long long)fmap(s) << 13) |
                                            (unsigned long long)(8191 - code));
                }
            }
        }
    }
}

// -------- Kernel D: fused epilogue, 256 blocks (R17-identical) -----------------
__global__ __launch_bounds__(256) void k_final(const unsigned long long* __restrict__ packed,
                                               const float* __restrict__ zn,
                                               const float* __restrict__ emb,
                                               const float* __restrict__ cs,
                                               float* __restrict__ out) {
    __shared__ float lesum[32][32];               // 4 KiB
    __shared__ int lbins[32];
    __shared__ int lsid[32];
    __shared__ float ls4[4];

    int blk = blockIdx.x, t = threadIdx.x;
    int wave = t >> 6, lane = t & 63;
    int tok0 = blk * 32, kbase = blk * 32;

    if (t < 32) lbins[t] = 0;
#pragma unroll
    for (int i = 0; i < 4; ++i) {
        int idx = i * 256 + t;
        lesum[idx >> 5][idx & 31] = 0.f;
    }
    if (t < 32) {                                 // unpack ids for our tokens
        int n = tok0 + t;
        int id = 8191 - (int)(packed[n] & 8191ull);
        lsid[t] = id;
        out[OUT_IDS + n] = (float)id;
    }
    __syncthreads();

    // ---- z_q gather + transpose-out + loss partial ----
    float s = 0.f;
#pragma unroll
    for (int i = 0; i < 4; ++i) {
        int idx = i * 256 + t;
        int tl = idx >> 5, c = idx & 31;
        int n = tok0 + tl;
        int id = lsid[tl];
        float ev = emb[(size_t)id * CDIM + c];    // <=32 rows, L1/L2
        float zv = zn[(size_t)n * CDIM + c];      // coalesced row reads
        int b = n >> 8, hw = n & 255;
        out[OUT_ZQ + ((size_t)b * CDIM + c) * HW + hw] = ev;
        float dd = ev - zv;
        s += dd * dd;
    }
#pragma unroll
    for (int off = 32; off > 0; off >>= 1) s += __shfl_down(s, off);
    if (lane == 0) ls4[wave] = s;
    __syncthreads();
    if (t == 0)
        atomicAdd(out + OUT_LOSS,
                  (ls4[0] + ls4[1] + ls4[2] + ls4[3]) * (1.0f / 262144.0f));

    // ---- bins + esum: scan all tokens for hits in our code window ----
    for (int i = 0; i < 32; ++i) {
        int n = i * 256 + t;                      // coalesced
        int id = 8191 - (int)(packed[n] & 8191ull);
        unsigned kl = (unsigned)(id - kbase);
        if (kl < 32u) {                           // ~8 hits per wave total
            atomicAdd(&lbins[kl], 1);
            const float* zp = zn + (size_t)n * CDIM;
#pragma unroll
            for (int c = 0; c < CDIM; ++c)
                atomicAdd(&lesum[kl][c], zp[c]);
        }
    }
    __syncthreads();

    // ---- EMA update + renormalize for our 32 codes ----
#pragma unroll
    for (int i = 0; i < 4; ++i) {
        int idx = i * 256 + t;
        int kl = idx >> 5, c = idx & 31;
        int k = kbase + kl;
        int bi = lbins[kl];
        float bf = (float)bi;
        bool zero = (bi == 0);
        float tv = lesum[kl][c] / (zero ? 1.0f : bf);
        float ss = tv * tv;
#pragma unroll
        for (int sh = 1; sh < 32; sh <<= 1) ss += __shfl_xor(ss, sh);
        float d = fmaxf(sqrtf(ss), 1e-12f);
        float ew = emb[(size_t)k * CDIM + c];
        float en = zero ? ew : (tv / d);
        float w = ew * DECAYF + (1.0f - DECAYF) * en;
        float ss2 = w * w;
#pragma unroll
        for (int sh = 1; sh < 32; sh <<= 1) ss2 += __shfl_xor(ss2, sh);
        float d2 = fmaxf(sqrtf(ss2), 1e-12f);
        out[OUT_EMB + (size_t)k * CDIM + c] = w / d2;
        if (c == 0) out[OUT_CS + k] = cs[k] * DECAYF + (1.0f - DECAYF) * bf;
    }
}

extern "C" void kernel_launch(void* const* d_in, const int* in_sizes, int n_in,
                              void* d_out, int out_size, void* d_ws, size_t ws_size,
                              hipStream_t stream) {
    const float* z   = (const float*)d_in[0];   // [32,32,16,16]
    const float* emb = (const float*)d_in[1];   // [8192,32]
    const float* cs  = (const float*)d_in[2];   // [8192]
    float* out = (float*)d_out;
    char* ws = (char*)d_ws;

    float* zn                  = (float*)(ws + WS_ZN);
    unsigned short* znbf       = (unsigned short*)(ws + WS_ZNBF);
    float* pmax                = (float*)(ws + WS_PMAX);
    unsigned long long* packed = (unsigned long long*)(ws + WS_PACK);

    k_prep<<<dim3(32), 256, 0, stream>>>(z, zn, znbf, packed, out);
    k_max<<<dim3(NTOK / 256, NCHUNK), 256, 0, stream>>>(znbf, emb, pmax);
    k_pick<<<dim3(NTOK / 256, NCHUNK), 256, 0, stream>>>(znbf, zn, emb, pmax, packed);
    k_final<<<dim3(256), 256, 0, stream>>>(packed, zn, emb, cs, out);
}

// Round 8
// 121.752 us; speedup vs baseline: 1.5048x; 1.5048x over previous
//
#include <hip/hip_runtime.h>

// NormEMAVectorQuantizer on MI355X (gfx950)
// N=8192 tokens, C=32, K=8192 codes, B=32, H*W=256.
// R25 = R24 with the spill fixed. R24 post-mortem: __launch_bounds__(256,4)
// on gfx950's UNIFIED VGPR/AGPR file split the 128-reg budget 64 arch + 64
// acc -> k_max/k_pick spilled ~580B/thread (WRITE_SIZE 148MB, FETCH 170MB,
// 83us). Fix: plain __launch_bounds__(256) (R17's proven shape: compiler
// picks ~110 VGPR -> 4 waves/SIMD, no spill), and staging pack via
// ext_vector (register-guaranteed) instead of a union.
// Kept from R24 (passed, numerics bit-identical to proven R17):
//  (a) ebf stage DELETED: sweeps stage emb fp32->bf16 in-register (same f2bf
//      rounding -> identical LDS image -> identical pmax/pick results).
//  (b) k_prep = 32 blocks: norm + packed[n]=0 folded + loss zero.
// k_final byte-identical to R17. Certificate (proven): bf16 dot err
// <= 2*2^-9 = 0.0078 < eps=0.01 for unit rows -> every code that can be the
// fp32 argmax (incl. ties) is exact-rescored in fp32; key =
// (fmap(s)<<13)|(8191-code) reproduces numpy lowest-index tie-break.
//
// Outputs (float32, concatenated):
//   [0 .. 262144)        z_q_out [B,C,H,W]
//   [262144]             loss (scalar)
//   [262145 .. 270337)   token_ids [B,H,W] as float
//   [270337 .. 532481)   new_embedding [K,C]
//   [532481 .. 540673)   new_cluster_sizes [K]

#define NTOK   8192
#define NCODE  8192
#define CDIM   32
#define HW     256
#define DECAYF 0.99f
#define EPSF   0.01f

#define OUT_ZQ   0
#define OUT_LOSS 262144
#define OUT_IDS  262145
#define OUT_EMB  270337
#define OUT_CS   532481

// workspace byte offsets
#define WS_ZN     0u        // f32 [N,C]        = 1048576
#define WS_ZNBF   1048576u  // bf16 [N,C]       = 524288
#define WS_PMAX   1572864u  // f32 [32][N]      = 1048576
#define WS_PACK   2621440u  // u64 [N]          = 65536   (end 2686976)

#define CHUNK  256
#define NCHUNK (NCODE / CHUNK)  // 32
#define TILES  (CHUNK / 16)     // 16

typedef __attribute__((ext_vector_type(8))) short bf16x8;
typedef __attribute__((ext_vector_type(8))) unsigned short u16x8;
typedef __attribute__((ext_vector_type(4))) float f32x4;

__device__ inline unsigned short f2bf(float x) {
    unsigned u = __float_as_uint(x);
    return (unsigned short)((u + 0x7FFFu + ((u >> 16) & 1u)) >> 16);
}
__device__ inline unsigned fmap(float s) {   // monotonic f32 -> u32
    unsigned u = __float_as_uint(s);
    return (u & 0x80000000u) ? ~u : (u | 0x80000000u);
}

// stage one 256x32 chunk of fp32 emb into LDS as bf16, rows padded to 5
// float4 units (80B): banks cycle 20*row%32 -> max 2-way conflict (free).
// Identical LDS image to R17's ebf staging (same f2bf rounding). All vector
// lanes statically indexed -> registers (no union, no scratch).
__device__ inline void stage_chunk_f32(const float* __restrict__ emb,
                                       int kbase, float4* lbs5, int t) {
    const float* src = emb + (size_t)kbase * CDIM;
#pragma unroll
    for (int j = 0; j < 4; ++j) {
        int u = t + j * 256, row = u >> 2, seg = u & 3;
        const float4* p = (const float4*)(src + row * CDIM + seg * 8);
        float4 x4 = p[0], y4 = p[1];
        u16x8 w;
        w[0] = f2bf(x4.x); w[1] = f2bf(x4.y); w[2] = f2bf(x4.z); w[3] = f2bf(x4.w);
        w[4] = f2bf(y4.x); w[5] = f2bf(y4.y); w[6] = f2bf(y4.z); w[7] = f2bf(y4.w);
        *(u16x8*)(lbs5 + row * 5 + seg) = w;
    }
}

// -------- Kernel A: prep, 32 blocks: norm + zero packed + zero loss -----------
__global__ __launch_bounds__(256) void k_prep(const float* __restrict__ z,
                                              float* __restrict__ zn,
                                              unsigned short* __restrict__ znbf,
                                              unsigned long long* __restrict__ packed,
                                              float* __restrict__ out) {
    int bid = blockIdx.x, t = threadIdx.x;
    int n = bid * 256 + t;
    int b = n >> 8, hw = n & 255;
    const float* zp = z + (size_t)b * (CDIM * HW) + hw;
    float v[CDIM];
    float ss = 0.f;
#pragma unroll
    for (int c = 0; c < CDIM; ++c) {
        float tv = zp[c * HW];                    // coalesced per c
        v[c] = tv;
        ss += tv * tv;
    }
    float d = fmaxf(sqrtf(ss), 1e-12f);
    float* o = zn + (size_t)n * CDIM;
    unsigned short* ob = znbf + (size_t)n * CDIM;
#pragma unroll
    for (int c = 0; c < CDIM; ++c) {
        float tv = v[c] / d;
        o[c] = tv;
        ob[c] = f2bf(tv);
    }
    packed[n] = 0ull;                             // zero for k_pick's atomicMax
    if (bid == 0 && t == 0) out[OUT_LOSS] = 0.f;
}

// -------- Kernel B: MFMA sweep -> pmax[chunk][tok] -----------------------------
__global__ __launch_bounds__(256) void k_max(const unsigned short* __restrict__ znbf,
                                             const float* __restrict__ emb,
                                             float* __restrict__ pmax) {
    __shared__ float4 lbs5[CHUNK * 5];            // 20 KiB, 80B rows
    __shared__ float lmax[256];
    int kbase = blockIdx.y * CHUNK;
    stage_chunk_f32(emb, kbase, lbs5, threadIdx.x);
    __syncthreads();

    int wave = threadIdx.x >> 6, lane = threadIdx.x & 63;
    int col = lane & 15, quad = lane >> 4;
    int wtok = blockIdx.x * 256 + wave * 64;

    bf16x8 a[4];                                  // 4 frags = 64 tokens
#pragma unroll
    for (int f = 0; f < 4; ++f)
        a[f] = *(const bf16x8*)(znbf + (size_t)(wtok + f * 16 + col) * CDIM + quad * 8);

    const bf16x8* bl = (const bf16x8*)lbs5;       // 16B units, row stride 5
    const f32x4 zero4 = {0.f, 0.f, 0.f, 0.f};
    float m[4][4];
#pragma unroll
    for (int f = 0; f < 4; ++f)
#pragma unroll
        for (int r = 0; r < 4; ++r) m[f][r] = -1e30f;

    for (int t = 0; t < TILES; ++t) {
        bf16x8 b = bl[(t * 16 + col) * 5 + quad];
#pragma unroll
        for (int f = 0; f < 4; ++f) {
            f32x4 d = __builtin_amdgcn_mfma_f32_16x16x32_bf16(a[f], b, zero4, 0, 0, 0);
#pragma unroll
            for (int r = 0; r < 4; ++r) m[f][r] = fmaxf(m[f][r], d[r]);
        }
    }
#pragma unroll
    for (int f = 0; f < 4; ++f)
#pragma unroll
        for (int r = 0; r < 4; ++r) {
            float v = m[f][r];
#pragma unroll
            for (int s = 1; s < 16; s <<= 1) v = fmaxf(v, __shfl_xor(v, s));
            if (col == 0) lmax[wave * 64 + f * 16 + quad * 4 + r] = v;
        }
    __syncthreads();
    pmax[(size_t)blockIdx.y * NTOK + blockIdx.x * 256 + threadIdx.x] = lmax[threadIdx.x];
}

// -------- Kernel C: dense rescan vs gmax-eps + inline exact fp32 rescore -------
__global__ __launch_bounds__(256) void k_pick(const unsigned short* __restrict__ znbf,
                                              const float* __restrict__ zn,
                                              const float* __restrict__ emb,
                                              const float* __restrict__ pmax,
                                              unsigned long long* __restrict__ packed) {
    __shared__ float4 lbs5[CHUNK * 5];            // 20 KiB
    __shared__ float lthr[256];
    int kbase = blockIdx.y * CHUNK;
    stage_chunk_f32(emb, kbase, lbs5, threadIdx.x);
    {   // per-token global threshold: 32 coalesced loads
        int tok = blockIdx.x * 256 + threadIdx.x;
        float mx = -1e30f;
#pragma unroll
        for (int ch = 0; ch < NCHUNK; ++ch)
            mx = fmaxf(mx, pmax[(size_t)ch * NTOK + tok]);
        lthr[threadIdx.x] = mx - EPSF;
    }
    __syncthreads();

    int wave = threadIdx.x >> 6, lane = threadIdx.x & 63;
    int col = lane & 15, quad = lane >> 4;
    int wtok = blockIdx.x * 256 + wave * 64;

    bf16x8 a[4];
#pragma unroll
    for (int f = 0; f < 4; ++f)
        a[f] = *(const bf16x8*)(znbf + (size_t)(wtok + f * 16 + col) * CDIM + quad * 8);

    float thr[4][4];
#pragma unroll
    for (int f = 0; f < 4; ++f)
#pragma unroll
        for (int r = 0; r < 4; ++r)
            thr[f][r] = lthr[wave * 64 + f * 16 + quad * 4 + r];

    const bf16x8* bl = (const bf16x8*)lbs5;
    const f32x4 zero4 = {0.f, 0.f, 0.f, 0.f};

    for (int t = 0; t < TILES; ++t) {
        bf16x8 b = bl[(t * 16 + col) * 5 + quad];
#pragma unroll
        for (int f = 0; f < 4; ++f) {
            f32x4 d = __builtin_amdgcn_mfma_f32_16x16x32_bf16(a[f], b, zero4, 0, 0, 0);
#pragma unroll
            for (int r = 0; r < 4; ++r) {
                if (d[r] >= thr[f][r]) {          // rare: ~1.05/token total
                    int tok = wtok + f * 16 + quad * 4 + r;
                    int code = kbase + t * 16 + col;
                    const float* zp = zn + (size_t)tok * CDIM;
                    const float* ep = emb + (size_t)code * CDIM;
                    float a0 = 0.f, a1 = 0.f, a2 = 0.f, a3 = 0.f;
#pragma unroll
                    for (int j = 0; j < 8; ++j) {
                        a0 = __builtin_fmaf(zp[4 * j + 0], ep[4 * j + 0], a0);
                        a1 = __builtin_fmaf(zp[4 * j + 1], ep[4 * j + 1], a1);
                        a2 = __builtin_fmaf(zp[4 * j + 2], ep[4 * j + 2], a2);
                        a3 = __builtin_fmaf(zp[4 * j + 3], ep[4 * j + 3], a3);
                    }
                    float s = (a0 + a1) + (a2 + a3);
                    atomicMax(packed + tok, ((unsigned long long)fmap(s) << 13) |
                                            (unsigned long long)(8191 - code));
                }
            }
        }
    }
}

// -------- Kernel D: fused epilogue, 256 blocks (R17-identical) -----------------
__global__ __launch_bounds__(256) void k_final(const unsigned long long* __restrict__ packed,
                                               const float* __restrict__ zn,
                                               const float* __restrict__ emb,
                                               const float* __restrict__ cs,
                                               float* __restrict__ out) {
    __shared__ float lesum[32][32];               // 4 KiB
    __shared__ int lbins[32];
    __shared__ int lsid[32];
    __shared__ float ls4[4];

    int blk = blockIdx.x, t = threadIdx.x;
    int wave = t >> 6, lane = t & 63;
    int tok0 = blk * 32, kbase = blk * 32;

    if (t < 32) lbins[t] = 0;
#pragma unroll
    for (int i = 0; i < 4; ++i) {
        int idx = i * 256 + t;
        lesum[idx >> 5][idx & 31] = 0.f;
    }
    if (t < 32) {                                 // unpack ids for our tokens
        int n = tok0 + t;
        int id = 8191 - (int)(packed[n] & 8191ull);
        lsid[t] = id;
        out[OUT_IDS + n] = (float)id;
    }
    __syncthreads();

    // ---- z_q gather + transpose-out + loss partial ----
    float s = 0.f;
#pragma unroll
    for (int i = 0; i < 4; ++i) {
        int idx = i * 256 + t;
        int tl = idx >> 5, c = idx & 31;
        int n = tok0 + tl;
        int id = lsid[tl];
        float ev = emb[(size_t)id * CDIM + c];    // <=32 rows, L1/L2
        float zv = zn[(size_t)n * CDIM + c];      // coalesced row reads
        int b = n >> 8, hw = n & 255;
        out[OUT_ZQ + ((size_t)b * CDIM + c) * HW + hw] = ev;
        float dd = ev - zv;
        s += dd * dd;
    }
#pragma unroll
    for (int off = 32; off > 0; off >>= 1) s += __shfl_down(s, off);
    if (lane == 0) ls4[wave] = s;
    __syncthreads();
    if (t == 0)
        atomicAdd(out + OUT_LOSS,
                  (ls4[0] + ls4[1] + ls4[2] + ls4[3]) * (1.0f / 262144.0f));

    // ---- bins + esum: scan all tokens for hits in our code window ----
    for (int i = 0; i < 32; ++i) {
        int n = i * 256 + t;                      // coalesced
        int id = 8191 - (int)(packed[n] & 8191ull);
        unsigned kl = (unsigned)(id - kbase);
        if (kl < 32u) {                           // ~8 hits per wave total
            atomicAdd(&lbins[kl], 1);
            const float* zp = zn + (size_t)n * CDIM;
#pragma unroll
            for (int c = 0; c < CDIM; ++c)
                atomicAdd(&lesum[kl][c], zp[c]);
        }
    }
    __syncthreads();

    // ---- EMA update + renormalize for our 32 codes ----
#pragma unroll
    for (int i = 0; i < 4; ++i) {
        int idx = i * 256 + t;
        int kl = idx >> 5, c = idx & 31;
        int k = kbase + kl;
        int bi = lbins[kl];
        float bf = (float)bi;
        bool zero = (bi == 0);
        float tv = lesum[kl][c] / (zero ? 1.0f : bf);
        float ss = tv * tv;
#pragma unroll
        for (int sh = 1; sh < 32; sh <<= 1) ss += __shfl_xor(ss, sh);
        float d = fmaxf(sqrtf(ss), 1e-12f);
        float ew = emb[(size_t)k * CDIM + c];
        float en = zero ? ew : (tv / d);
        float w = ew * DECAYF + (1.0f - DECAYF) * en;
        float ss2 = w * w;
#pragma unroll
        for (int sh = 1; sh < 32; sh <<= 1) ss2 += __shfl_xor(ss2, sh);
        float d2 = fmaxf(sqrtf(ss2), 1e-12f);
        out[OUT_EMB + (size_t)k * CDIM + c] = w / d2;
        if (c == 0) out[OUT_CS + k] = cs[k] * DECAYF + (1.0f - DECAYF) * bf;
    }
}

extern "C" void kernel_launch(void* const* d_in, const int* in_sizes, int n_in,
                              void* d_out, int out_size, void* d_ws, size_t ws_size,
                              hipStream_t stream) {
    const float* z   = (const float*)d_in[0];   // [32,32,16,16]
    const float* emb = (const float*)d_in[1];   // [8192,32]
    const float* cs  = (const float*)d_in[2];   // [8192]
    float* out = (float*)d_out;
    char* ws = (char*)d_ws;

    float* zn                  = (float*)(ws + WS_ZN);
    unsigned short* znbf       = (unsigned short*)(ws + WS_ZNBF);
    float* pmax                = (float*)(ws + WS_PMAX);
    unsigned long long* packed = (unsigned long long*)(ws + WS_PACK);

    k_prep<<<dim3(32), 256, 0, stream>>>(z, zn, znbf, packed, out);
    k_max<<<dim3(NTOK / 256, NCHUNK), 256, 0, stream>>>(znbf, emb, pmax);
    k_pick<<<dim3(NTOK / 256, NCHUNK), 256, 0, stream>>>(znbf, zn, emb, pmax, packed);
    k_final<<<dim3(256), 256, 0, stream>>>(packed, zn, emb, cs, out);
}